// Round 16
// baseline (184.237 us; speedup 1.0000x reference)
//
#include <hip/hip_runtime.h>

#define B_ 2
#define C_ 3
#define H_ 512
#define W_ 512
#define F_ 5
#define T_ 25
#define HW_ (H_ * W_)
#define PW_ 520   // packed row stride in pixels (8B each)
#define PH_ 513   // packed rows; row 512 duplicates row 511 (border clamp)

// LDS tile geometry: block covers 32w x 8h outputs, halo +-10 px.
// Reshaped from 64x4 (r15): grid 1024->2048 blocks = 8 blocks/CU, lifting
// the occupancy cap from 50% (grid-limited, measured 40-46%) to 100%.
// Latency-bound kernel (no pipe >41%) -> more resident waves = more hiding.
// Squarer tile also stages FEWER px per output (1566 vs 2200 per 256 out).
#define TBW 32
#define TBH 8
#define RY  10
#define RX  10
#define TRH (TBH + 2 * RY + 1)   // 29 rows
#define TCW 54                   // >= TBW + 2*RX + 2
#define TILE_N (TRH * TCW)       // 1566 entries * 8B = 12.5 KB

// Streaming loads: NT hints are ESSENTIAL (measured r3 vs r14: 42us vs
// 75us dispatch). The 157MB offset/mask streams have zero reuse; NT keeps
// them from sweeping L2, so the reused pk tile rows stay L2-resident.
// FETCH_SIZE identical either way (90MB) -- L2-latency effect, not traffic.
#define NT(p) __builtin_nontemporal_load(p)

typedef _Float16 h4 __attribute__((ext_vector_type(4), aligned(8)));

// Repack planar f32 [B][C][H][W] -> fp16x4-packed [B][PH_][PW_] with
// duplicated clamp column (x=512 == x=511) and clamp row (row 512 == 511).
__global__ __launch_bounds__(256) void repack_kernel(
    const float* __restrict__ inp, h4* __restrict__ pk)
{
    const int x   = (blockIdx.x << 8) + threadIdx.x;   // 0..511
    const int row = blockIdx.y;                        // 0..512
    const int b   = blockIdx.z;
    const int sr  = row < H_ ? row : H_ - 1;
    const float* p = inp + b * (C_ * HW_) + (sr << 9) + x;
    h4 v;
    v.x = (_Float16)p[0];
    v.y = (_Float16)p[HW_];
    v.z = (_Float16)p[2 * HW_];
    v.w = (_Float16)0.f;
    h4* dst = pk + b * (PH_ * PW_) + row * PW_;
    dst[x] = v;
    if (x == W_ - 1) dst[W_] = v;   // duplicate clamp column
}

// Session ledger (rounds 3-15, measured):
//  - 64x4 baseline: 182.6-184.0 us total, ~42 us dispatch, VGPR 40,
//    Occupancy 40-46% (grid-limited: 1024 blocks = 4/CU = 50% cap).
//  - rolled fy + prefetch: neutral. 2 px/thread: SPILLED (322us). NT
//    removal: 75us dispatch (L2 stream pollution). Keep NT, keep unrolled.
//  - LDS bank conflicts (5.08M cyc) random-gather-inherent; swizzle no-op.
//  - ~138us of total is harness fill/reset (268MB fillBuffer @ 40us each),
//    not kernel-addressable.
// This round: tile reshape 64x4 -> 32x8 (grid 2048 = 8 blocks/CU) to lift
// the grid-limited occupancy cap. Per-thread tap code unchanged.
__global__ __launch_bounds__(256) void dsepconv_kernel(
    const h4* __restrict__ pk,       // packed input
    const float* __restrict__ vert,
    const float* __restrict__ horz,
    const float* __restrict__ offx,
    const float* __restrict__ offy,
    const float* __restrict__ mask,
    float* __restrict__ out)
{
    __shared__ h4 tile[TILE_N];

    const int tid = threadIdx.x;
    const int cl  = tid & 31;                   // column within tile 0..31
    const int cr  = tid >> 5;                   // row within tile    0..7
    const int h0  = blockIdx.y * TBH;
    const int w0b = blockIdx.x * TBW;
    const int b   = blockIdx.z;
    const int h   = h0 + cr;
    const int w   = w0b + cl;

    const int hw = (h << 9) | w;

    const float* vb   = vert + b * (F_ * HW_) + hw;
    const float* hb   = horz + b * (F_ * HW_) + hw;
    const float* ob_x = offx + b * (T_ * HW_) + hw;
    const float* ob_y = offy + b * (T_ * HW_) + hw;
    const float* mb   = mask + b * (T_ * HW_) + hw;
    const h4* pb      = pk + b * (PH_ * PW_);

    // filter values (issued early, overlap staging)
    float v[F_], hz[F_];
#pragma unroll
    for (int f = 0; f < F_; ++f) v[f]  = NT(vb + f * HW_);
#pragma unroll
    for (int f = 0; f < F_; ++f) hz[f] = NT(hb + f * HW_);

    // ---- stage input tile + halo into LDS (division-free) ----
    {
        const int colg0 = w0b - RX + cl;
        const int gc0 = min(max(colg0, 0), W_);
        const int gc1 = min(max(colg0 + 32, 0), W_);
#pragma unroll
        for (int r0 = 0; r0 < 4; ++r0) {
            const int r = r0 * 8 + cr;          // 0..31
            if (r < TRH) {                      // 29 rows
                const int gr = min(max(h0 - RY + r, 0), H_);  // 0..512
                const h4* src = pb + gr * PW_;
                tile[r * TCW + cl] = src[gc0];
                if (cl < TCW - 32)              // cl < 22
                    tile[r * TCW + 32 + cl] = src[gc1];
            }
        }
    }
    __syncthreads();

    float acc0 = 0.f, acc1 = 0.f, acc2 = 0.f;

    // tap position relative to tile origin:
    //   ixf_tile = oy + (cl + RX + fx - 1.5), clamped to tile
    const float xbase = (float)(cl + RX) - 1.5f;
    const float ybase = (float)(cr + RY) - 1.5f;
    // Reference border clamp folded into tile coords:
    const float xlo = -0.5f - (float)(w0b - RX);
    const float xhi = ((float)W_ - 0.5f) - (float)(w0b - RX);
    const float ylo = -0.5f - (float)(h0 - RY);
    const float yhi = ((float)H_ - 0.5f) - (float)(h0 - RY);

#pragma unroll
    for (int fy = 0; fy < F_; ++fy) {
        // row-batched streaming loads (15), consumed below in this iteration
        float cy[F_], cx[F_], cm[F_];
#pragma unroll
        for (int fx = 0; fx < F_; ++fx) {
            const int t = fy * F_ + fx;
            cy[fx] = NT(ob_y + t * HW_);
            cx[fx] = NT(ob_x + t * HW_);
            cm[fx] = NT(mb   + t * HW_);
        }

        const float vfy = v[fy];
        const float fyf = (float)fy;

#pragma unroll
        for (int fx = 0; fx < F_; ++fx) {
            const float oy = cy[fx];
            const float ox = cx[fx];
            const float m  = cm[fx];

            // tile-space sample coords with the reference border clamp
            float ixf = oy + (xbase + (float)fx);
            float iyf = ox + (ybase + fyf);
            ixf = fminf(fmaxf(ixf, xlo), xhi);
            iyf = fminf(fmaxf(iyf, ylo), yhi);

            float x0f = floorf(ixf), y0f = floorf(iyf);
            // floor==-1 at global border: all weight on left/top sample
            float wx1 = (ixf - x0f);
            float wy1 = (iyf - y0f);
            wx1 = (x0f < xlo) ? 0.f : wx1;   // only true at global left edge
            wy1 = (y0f < ylo) ? 0.f : wy1;

            // branchless tile clamp (memory safety for ~1e-17 prob taps)
            const int tc = min(max((int)x0f, 0), TCW - 2);
            const int ty = min(max((int)y0f, 0), TRH - 2);

            const h4* p = &tile[ty * TCW + tc];
            const h4 t00 = p[0];
            const h4 t01 = p[1];
            const h4 t10 = p[TCW];
            const h4 t11 = p[TCW + 1];

            // fp16 packed bilinear: x-lerp then y-lerp, 3 cvts at the end
            const _Float16 wx1h = (_Float16)wx1;
            const _Float16 wx0h = (_Float16)1.f - wx1h;
            const _Float16 wy1h = (_Float16)wy1;
            const _Float16 wy0h = (_Float16)1.f - wy1h;
            const h4 wx0v = { wx0h, wx0h, wx0h, wx0h };
            const h4 wx1v = { wx1h, wx1h, wx1h, wx1h };
            const h4 wy0v = { wy0h, wy0h, wy0h, wy0h };
            const h4 wy1v = { wy1h, wy1h, wy1h, wy1h };

            const h4 rt = t00 * wx0v + t01 * wx1v;
            const h4 rb = t10 * wx0v + t11 * wx1v;
            const h4 r  = rt * wy0v + rb * wy1v;

            const float coef = vfy * hz[fx] * m;
            acc0 += coef * (float)r.x;
            acc1 += coef * (float)r.y;
            acc2 += coef * (float)r.z;
        }
    }

    float* ob = out + b * (C_ * HW_) + hw;
    __builtin_nontemporal_store(acc0, ob);
    __builtin_nontemporal_store(acc1, ob + HW_);
    __builtin_nontemporal_store(acc2, ob + 2 * HW_);
}

extern "C" void kernel_launch(void* const* d_in, const int* in_sizes, int n_in,
                              void* d_out, int out_size, void* d_ws, size_t ws_size,
                              hipStream_t stream) {
    const float* inp  = (const float*)d_in[0];
    const float* vert = (const float*)d_in[1];
    const float* horz = (const float*)d_in[2];
    const float* offx = (const float*)d_in[3];
    const float* offy = (const float*)d_in[4];
    const float* mask = (const float*)d_in[5];
    float* out = (float*)d_out;
    h4* pk = (h4*)d_ws;   // B * 513 * 520 * 8B = 4.27 MB

    dim3 blockR(256), gridR(W_ / 256, PH_, B_);
    hipLaunchKernelGGL(repack_kernel, gridR, blockR, 0, stream, inp, pk);

    dim3 block(256);
    dim3 grid(W_ / TBW, H_ / TBH, B_);   // 16 x 64 x 2 = 2048 blocks
    hipLaunchKernelGGL(dsepconv_kernel, grid, block, 0, stream,
                       pk, vert, horz, offx, offy, mask, out);
}

// Round 17
// 183.180 us; speedup vs baseline: 1.0058x; 1.0058x over previous
//
#include <hip/hip_runtime.h>

#define B_ 2
#define C_ 3
#define H_ 512
#define W_ 512
#define F_ 5
#define T_ 25
#define HW_ (H_ * W_)
#define PW_ 520   // packed row stride in pixels (8B each)
#define PH_ 513   // packed rows; row 512 duplicates row 511 (border clamp)

// LDS tile geometry: block covers 32w x 16h outputs, halo +-10 px.
// r16 measured: occupancy pinned ~50% regardless of grid (41us flat), no
// pipe >45% -> per-wave dependent-chain bound. This round: 2 px/thread
// (rows cr and cr+8) with the UNROLLED body -- doubles independent chains
// per wave at fixed residency. Unlike r11's spill (rolled pipeline arrays,
// VGPR>128), the unrolled structure measured VGPR 28; 2px lands ~60-75.
#define TBW 32
#define TBH 16
#define RY  10
#define RX  10
#define TRH (TBH + 2 * RY + 1)   // 37 rows
#define TCW 54                   // >= TBW + 2*RX + 2
#define TILE_N (TRH * TCW)       // 1998 entries * 8B = 16.0 KB

// NT hints on streams are ESSENTIAL (r3 vs r14: 42us vs 75us dispatch).
// Zero-reuse offset/mask streams must not sweep L2; pk tile rows must stay
// L2-resident. FETCH_SIZE identical either way -- L2-latency effect.
#define NT(p) __builtin_nontemporal_load(p)

typedef _Float16 h4 __attribute__((ext_vector_type(4), aligned(8)));

// Repack planar f32 [B][C][H][W] -> fp16x4-packed [B][PH_][PW_] with
// duplicated clamp column (x=512 == x=511) and clamp row (row 512 == 511).
__global__ __launch_bounds__(256) void repack_kernel(
    const float* __restrict__ inp, h4* __restrict__ pk)
{
    const int x   = (blockIdx.x << 8) + threadIdx.x;   // 0..511
    const int row = blockIdx.y;                        // 0..512
    const int b   = blockIdx.z;
    const int sr  = row < H_ ? row : H_ - 1;
    const float* p = inp + b * (C_ * HW_) + (sr << 9) + x;
    h4 v;
    v.x = (_Float16)p[0];
    v.y = (_Float16)p[HW_];
    v.z = (_Float16)p[2 * HW_];
    v.w = (_Float16)0.f;
    h4* dst = pk + b * (PH_ * PW_) + row * PW_;
    dst[x] = v;
    if (x == W_ - 1) dst[W_] = v;   // duplicate clamp column
}

// Session ledger (measured): 64x4 & 32x8 1px: ~41-42us dispatch, 182.6-184.2
// total. Rolled+prefetch: neutral. 2px rolled: SPILLED. NT removal: 75us.
// Occupancy pinned ~50% regardless of grid -> TLP dead, ILP is the lever.
// ~138us of total is harness fill/reset, not kernel-addressable.
__global__ __launch_bounds__(256) void dsepconv_kernel(
    const h4* __restrict__ pk,       // packed input
    const float* __restrict__ vert,
    const float* __restrict__ horz,
    const float* __restrict__ offx,
    const float* __restrict__ offy,
    const float* __restrict__ mask,
    float* __restrict__ out)
{
    __shared__ h4 tile[TILE_N];

    const int tid = threadIdx.x;
    const int cl  = tid & 31;                   // column within tile 0..31
    const int cr  = tid >> 5;                   // row within tile    0..7
    const int h0  = blockIdx.y * TBH;
    const int w0b = blockIdx.x * TBW;
    const int b   = blockIdx.z;
    const int w   = w0b + cl;

    const int hwA = ((h0 + cr) << 9) | w;       // pixel A: row h0+cr
    const int hwB = hwA + (8 << 9);             // pixel B: row h0+cr+8

    const float* vbA  = vert + b * (F_ * HW_) + hwA;
    const float* vbB  = vert + b * (F_ * HW_) + hwB;
    const float* hbA  = horz + b * (F_ * HW_) + hwA;
    const float* hbB  = horz + b * (F_ * HW_) + hwB;
    const float* oxA  = offx + b * (T_ * HW_) + hwA;
    const float* oxB  = offx + b * (T_ * HW_) + hwB;
    const float* oyA  = offy + b * (T_ * HW_) + hwA;
    const float* oyB  = offy + b * (T_ * HW_) + hwB;
    const float* mbA  = mask + b * (T_ * HW_) + hwA;
    const float* mbB  = mask + b * (T_ * HW_) + hwB;
    const h4* pb      = pk + b * (PH_ * PW_);

    // filter values (issued early, overlap staging)
    float vA[F_], hzA[F_], vB[F_], hzB[F_];
#pragma unroll
    for (int f = 0; f < F_; ++f) { vA[f] = NT(vbA + f * HW_); vB[f] = NT(vbB + f * HW_); }
#pragma unroll
    for (int f = 0; f < F_; ++f) { hzA[f] = NT(hbA + f * HW_); hzB[f] = NT(hbB + f * HW_); }

    // ---- stage input tile + halo into LDS (division-free) ----
    {
        const int colg0 = w0b - RX + cl;
        const int gc0 = min(max(colg0, 0), W_);
        const int gc1 = min(max(colg0 + 32, 0), W_);
#pragma unroll
        for (int r0 = 0; r0 < 5; ++r0) {
            const int r = r0 * 8 + cr;          // 0..39
            if (r < TRH) {                      // 37 rows
                const int gr = min(max(h0 - RY + r, 0), H_);  // 0..512
                const h4* src = pb + gr * PW_;
                tile[r * TCW + cl] = src[gc0];
                if (cl < TCW - 32)              // cl < 22
                    tile[r * TCW + 32 + cl] = src[gc1];
            }
        }
    }
    __syncthreads();

    float aA0 = 0.f, aA1 = 0.f, aA2 = 0.f;
    float aB0 = 0.f, aB1 = 0.f, aB2 = 0.f;

    // tap position relative to tile origin
    const float xbase  = (float)(cl + RX) - 1.5f;
    const float ybaseA = (float)(cr + RY) - 1.5f;
    const float ybaseB = ybaseA + 8.f;
    // Reference border clamp folded into tile coords (block-level):
    const float xlo = -0.5f - (float)(w0b - RX);
    const float xhi = ((float)W_ - 0.5f) - (float)(w0b - RX);
    const float ylo = -0.5f - (float)(h0 - RY);
    const float yhi = ((float)H_ - 0.5f) - (float)(h0 - RY);

#pragma unroll
    for (int fy = 0; fy < F_; ++fy) {
        // row-batched streaming loads (30), consumed in this iteration
        float cyA[F_], cxA[F_], cmA[F_], cyB[F_], cxB[F_], cmB[F_];
#pragma unroll
        for (int fx = 0; fx < F_; ++fx) {
            const int t = fy * F_ + fx;
            cyA[fx] = NT(oyA + t * HW_);
            cxA[fx] = NT(oxA + t * HW_);
            cmA[fx] = NT(mbA + t * HW_);
            cyB[fx] = NT(oyB + t * HW_);
            cxB[fx] = NT(oxB + t * HW_);
            cmB[fx] = NT(mbB + t * HW_);
        }

        const float vfyA = vA[fy];
        const float vfyB = vB[fy];
        const float fyf  = (float)fy;

#pragma unroll
        for (int fx = 0; fx < F_; ++fx) {
            // ---- pixel A tap ----
            {
                float ixf = cyA[fx] + (xbase + (float)fx);
                float iyf = cxA[fx] + (ybaseA + fyf);
                ixf = fminf(fmaxf(ixf, xlo), xhi);
                iyf = fminf(fmaxf(iyf, ylo), yhi);
                float x0f = floorf(ixf), y0f = floorf(iyf);
                float wx1 = ixf - x0f, wy1 = iyf - y0f;
                wx1 = (x0f < xlo) ? 0.f : wx1;
                wy1 = (y0f < ylo) ? 0.f : wy1;
                const int tc = min(max((int)x0f, 0), TCW - 2);
                const int ty = min(max((int)y0f, 0), TRH - 2);
                const h4* p = &tile[ty * TCW + tc];
                const h4 t00 = p[0], t01 = p[1], t10 = p[TCW], t11 = p[TCW + 1];
                const _Float16 wx1h = (_Float16)wx1;
                const _Float16 wx0h = (_Float16)1.f - wx1h;
                const _Float16 wy1h = (_Float16)wy1;
                const _Float16 wy0h = (_Float16)1.f - wy1h;
                const h4 wx0v = { wx0h, wx0h, wx0h, wx0h };
                const h4 wx1v = { wx1h, wx1h, wx1h, wx1h };
                const h4 wy0v = { wy0h, wy0h, wy0h, wy0h };
                const h4 wy1v = { wy1h, wy1h, wy1h, wy1h };
                const h4 rt = t00 * wx0v + t01 * wx1v;
                const h4 rb = t10 * wx0v + t11 * wx1v;
                const h4 r  = rt * wy0v + rb * wy1v;
                const float coef = vfyA * hzA[fx] * cmA[fx];
                aA0 += coef * (float)r.x;
                aA1 += coef * (float)r.y;
                aA2 += coef * (float)r.z;
            }
            // ---- pixel B tap (independent chain) ----
            {
                float ixf = cyB[fx] + (xbase + (float)fx);
                float iyf = cxB[fx] + (ybaseB + fyf);
                ixf = fminf(fmaxf(ixf, xlo), xhi);
                iyf = fminf(fmaxf(iyf, ylo), yhi);
                float x0f = floorf(ixf), y0f = floorf(iyf);
                float wx1 = ixf - x0f, wy1 = iyf - y0f;
                wx1 = (x0f < xlo) ? 0.f : wx1;
                wy1 = (y0f < ylo) ? 0.f : wy1;
                const int tc = min(max((int)x0f, 0), TCW - 2);
                const int ty = min(max((int)y0f, 0), TRH - 2);
                const h4* p = &tile[ty * TCW + tc];
                const h4 t00 = p[0], t01 = p[1], t10 = p[TCW], t11 = p[TCW + 1];
                const _Float16 wx1h = (_Float16)wx1;
                const _Float16 wx0h = (_Float16)1.f - wx1h;
                const _Float16 wy1h = (_Float16)wy1;
                const _Float16 wy0h = (_Float16)1.f - wy1h;
                const h4 wx0v = { wx0h, wx0h, wx0h, wx0h };
                const h4 wx1v = { wx1h, wx1h, wx1h, wx1h };
                const h4 wy0v = { wy0h, wy0h, wy0h, wy0h };
                const h4 wy1v = { wy1h, wy1h, wy1h, wy1h };
                const h4 rt = t00 * wx0v + t01 * wx1v;
                const h4 rb = t10 * wx0v + t11 * wx1v;
                const h4 r  = rt * wy0v + rb * wy1v;
                const float coef = vfyB * hzB[fx] * cmB[fx];
                aB0 += coef * (float)r.x;
                aB1 += coef * (float)r.y;
                aB2 += coef * (float)r.z;
            }
        }
    }

    float* obA = out + b * (C_ * HW_) + hwA;
    float* obB = out + b * (C_ * HW_) + hwB;
    __builtin_nontemporal_store(aA0, obA);
    __builtin_nontemporal_store(aA1, obA + HW_);
    __builtin_nontemporal_store(aA2, obA + 2 * HW_);
    __builtin_nontemporal_store(aB0, obB);
    __builtin_nontemporal_store(aB1, obB + HW_);
    __builtin_nontemporal_store(aB2, obB + 2 * HW_);
}

extern "C" void kernel_launch(void* const* d_in, const int* in_sizes, int n_in,
                              void* d_out, int out_size, void* d_ws, size_t ws_size,
                              hipStream_t stream) {
    const float* inp  = (const float*)d_in[0];
    const float* vert = (const float*)d_in[1];
    const float* horz = (const float*)d_in[2];
    const float* offx = (const float*)d_in[3];
    const float* offy = (const float*)d_in[4];
    const float* mask = (const float*)d_in[5];
    float* out = (float*)d_out;
    h4* pk = (h4*)d_ws;   // B * 513 * 520 * 8B = 4.27 MB

    dim3 blockR(256), gridR(W_ / 256, PH_, B_);
    hipLaunchKernelGGL(repack_kernel, gridR, blockR, 0, stream, inp, pk);

    dim3 block(256);
    dim3 grid(W_ / TBW, H_ / TBH, B_);   // 16 x 32 x 2 = 1024 blocks
    hipLaunchKernelGGL(dsepconv_kernel, grid, block, 0, stream,
                       pk, vert, horz, offx, offy, mask, out);
}